// Round 5
// baseline (1596.100 us; speedup 1.0000x reference)
//
#include <hip/hip_runtime.h>
#include <hip/hip_bf16.h>
#include <math.h>

typedef __attribute__((ext_vector_type(4))) float f32x4;
typedef __attribute__((ext_vector_type(8))) short s16x8;
typedef __attribute__((ext_vector_type(4))) short s16x4;

#define BB 2
#define SS 1024
#define MEM 1024
#define DD 1024
#define LL 4
#define VV 32000
#define TT 2048
#define NH 16
#define DH 64

__device__ __forceinline__ short f2bf(float f) {
    unsigned u = __float_as_uint(f);
    u += 0x7fffu + ((u >> 16) & 1u);   // round-to-nearest-even
    return (short)(u >> 16);
}

__device__ __forceinline__ float gelu_f(float x) {
    return 0.5f * x * (1.0f + erff(x * 0.70710678118654752f));
}

__device__ __forceinline__ void gll16(const short* g, short* l) {
    __builtin_amdgcn_global_load_lds(
        (__attribute__((address_space(1))) void*)(short*)g,
        (__attribute__((address_space(3))) void*)l, 16, 0, 0);
}

// ---------------- GEMM: C(M,N) = act(A @ Bt^T + bias), bf16 inputs --------
// A [M][K] bf16; Bt [N][K] bf16 (pre-transposed weight).
// Double-buffered LDS, ONE barrier per K-step: stage(buf[t+1]) right after
// the barrier so the next barrier's vmcnt(0) drain is covered by this step's
// ds_read+MFMA. 1D grid, XCD-chunked column-major swizzle (B-panel L2 reuse).
// LDS slot layout: slot s (16B) = [block16 = s>>7][kslice = (s>>4)&7][fr = s&15]
// -> conflict-free ds_read_b128 frag reads (verified: 0 conflicts in R3).
template<int WM, int WN>
__global__ __launch_bounds__(256) void gemm_bf16(
    const short* __restrict__ A, const short* __restrict__ Bt,
    const float* __restrict__ bias, const float* __restrict__ bias2,
    int nsplit, void* __restrict__ Cv, int N, int K, int nby, int act, int obf)
{
    constexpr int BM = WM * 32, BN = WN * 32;
    constexpr int NA = BM / 32, NB = BN / 32;   // 16B gll slots per thread
    constexpr int ASZ = BM * 64, BSZ = BN * 64; // shorts per buffer
    __shared__ short a_s[2 * ASZ];
    __shared__ short b_s[2 * BSZ];
    const int tid  = threadIdx.x;
    const int lane = tid & 63;
    const int wave = tid >> 6;
    const int wr = wave >> 1, wc = wave & 1;
    const int fr = lane & 15, fg = lane >> 4;

    const int nwg = gridDim.x;
    const int bid = blockIdx.x;
    const int swz = ((nwg & 7) == 0) ? ((bid & 7) * (nwg >> 3) + (bid >> 3)) : bid;
    const size_t m0 = (size_t)(swz % nby) * BM;   // M fastest -> B-panel reuse
    const size_t n0 = (size_t)(swz / nby) * BN;

    const short* gA[NA]; short* lA[NA];
    const short* gB[NB]; short* lB[NB];
    #pragma unroll
    for (int i = 0; i < NA; ++i) {
        const int s   = i * 256 + tid;
        const int row = (s >> 7) * 16 + (s & 15);
        const int kof = ((s >> 4) & 7) * 8;
        gA[i] = A + (m0 + row) * (size_t)K + kof;
        lA[i] = &a_s[s * 8];
    }
    #pragma unroll
    for (int i = 0; i < NB; ++i) {
        const int s   = i * 256 + tid;
        const int nn  = (s >> 7) * 16 + (s & 15);
        const int kof = ((s >> 4) & 7) * 8;
        gB[i] = Bt + (n0 + nn) * (size_t)K + kof;
        lB[i] = &b_s[s * 8];
    }

    f32x4 acc[WM][WN] = {};

    // prologue: stage K-step 0 into buffer 0
    #pragma unroll
    for (int i = 0; i < NA; ++i) gll16(gA[i], lA[i]);
    #pragma unroll
    for (int i = 0; i < NB; ++i) gll16(gB[i], lB[i]);

    const int nt = K >> 6;
    for (int t = 0; t < nt; ++t) {
        const int cur = t & 1;
        __syncthreads();   // compiler drains vmcnt(0)+lgkmcnt(0): buf[cur] ready,
                           // prior-step reads of buf[cur^1] retired
        if (t + 1 < nt) {  // issue next-tile stage NOW; drained by NEXT barrier
            const int koff = (t + 1) << 6;
            #pragma unroll
            for (int i = 0; i < NA; ++i) gll16(gA[i] + koff, lA[i] + (cur ^ 1) * ASZ);
            #pragma unroll
            for (int i = 0; i < NB; ++i) gll16(gB[i] + koff, lB[i] + (cur ^ 1) * BSZ);
        }
        const short* ab = &a_s[cur * ASZ];
        const short* bb = &b_s[cur * BSZ];
        s16x8 af[WM][2], bf[WN][2];
        #pragma unroll
        for (int mi = 0; mi < WM; ++mi)
            #pragma unroll
            for (int h = 0; h < 2; ++h)
                af[mi][h] = *(const s16x8*)&ab[((wr*WM + mi)*128 + (h*4 + fg)*16 + fr) * 8];
        #pragma unroll
        for (int ni = 0; ni < WN; ++ni)
            #pragma unroll
            for (int h = 0; h < 2; ++h)
                bf[ni][h] = *(const s16x8*)&bb[((wc*WN + ni)*128 + (h*4 + fg)*16 + fr) * 8];
        #pragma unroll
        for (int mi = 0; mi < WM; ++mi)
            #pragma unroll
            for (int ni = 0; ni < WN; ++ni) {
                acc[mi][ni] = __builtin_amdgcn_mfma_f32_16x16x32_bf16(
                    af[mi][0], bf[ni][0], acc[mi][ni], 0, 0, 0);
                acc[mi][ni] = __builtin_amdgcn_mfma_f32_16x16x32_bf16(
                    af[mi][1], bf[ni][1], acc[mi][ni], 0, 0, 0);
            }
    }

    float* Cf = (float*)Cv;
    short* Cb = (short*)Cv;
    #pragma unroll
    for (int mi = 0; mi < WM; ++mi) {
        #pragma unroll
        for (int ni = 0; ni < WN; ++ni) {
            const size_t r0 = m0 + wr*WM*16 + mi*16 + fg*4;
            const size_t c  = n0 + wc*WN*16 + ni*16 + fr;
            const float bb = (c < (size_t)nsplit) ? bias[c] : bias2[c - nsplit];
            #pragma unroll
            for (int rg = 0; rg < 4; ++rg) {
                float vv = acc[mi][ni][rg] + bb;
                if (act) vv = gelu_f(vv);
                if (obf) Cb[(r0 + rg)*(size_t)N + c] = f2bf(vv);
                else     Cf[(r0 + rg)*(size_t)N + c] = vv;
            }
        }
    }
}

// ---------------- weight transpose+convert: W[k][n] f32 -> Wt[n][k] bf16 ----
__global__ __launch_bounds__(256) void transpose7_kernel(
    const float* w0, const float* w1, const float* w2, const float* w3,
    const float* w4, const float* w5, const float* w6, short* out)
{
    __shared__ float t[32][33];
    const int z = blockIdx.z;
    const float* W;
    switch (z) {
        case 0: W = w0; break; case 1: W = w1; break; case 2: W = w2; break;
        case 3: W = w3; break; case 4: W = w4; break; case 5: W = w5; break;
        default: W = w6; break;
    }
    short* O = out + (size_t)z * DD * DD;
    const int tid = threadIdx.x;
    const int k0 = blockIdx.y * 32, n0 = blockIdx.x * 32;
    const int r = tid >> 3, c4 = (tid & 7) * 4;
    float4 v = *(const float4*)&W[(size_t)(k0 + r) * DD + n0 + c4];
    t[r][c4+0] = v.x; t[r][c4+1] = v.y; t[r][c4+2] = v.z; t[r][c4+3] = v.w;
    __syncthreads();
    short4 o;
    o.x = f2bf(t[c4+0][r]); o.y = f2bf(t[c4+1][r]);
    o.z = f2bf(t[c4+2][r]); o.w = f2bf(t[c4+3][r]);
    *(short4*)&O[(size_t)(n0 + r) * DD + k0 + c4] = o;
}

__global__ __launch_bounds__(256) void transposeF_kernel(
    const float* __restrict__ W, short* __restrict__ O)
{
    __shared__ float t[32][33];
    const int tid = threadIdx.x;
    const int k0 = blockIdx.y * 32, n0 = blockIdx.x * 32;
    const int r = tid >> 3, c4 = (tid & 7) * 4;
    float4 v = *(const float4*)&W[(size_t)(k0 + r) * VV + n0 + c4];
    t[r][c4+0] = v.x; t[r][c4+1] = v.y; t[r][c4+2] = v.z; t[r][c4+3] = v.w;
    __syncthreads();
    short4 o;
    o.x = f2bf(t[c4+0][r]); o.y = f2bf(t[c4+1][r]);
    o.z = f2bf(t[c4+2][r]); o.w = f2bf(t[c4+3][r]);
    *(short4*)&O[(size_t)(n0 + r) * DD + k0 + c4] = o;
}

// ---------------- MFMA flash attention, bf16 in/out ----------------
// k,v read with row stride kstr (fused kv buffer: v = kv + 1024).
__global__ __launch_bounds__(256) void attn_kernel(
    const short* __restrict__ q, const short* __restrict__ k,
    const short* __restrict__ v, const short* __restrict__ Qr,
    short* __restrict__ ctx, int kstr)
{
    __shared__ short q_s[32][72];
    __shared__ short k_s[32][72];
    __shared__ short qr_s[64][72];
    __shared__ short vT_s[64][40];   // [d][t^X], X = ((d>>3)&3)<<3
    __shared__ float a_t[32][37];
    __shared__ float b_t[32][68];
    __shared__ short p_s[32][40];
    __shared__ float row_m[32], row_l[32], row_sc[32];

    const int tid  = threadIdx.x;
    const int id   = blockIdx.x;
    const int bh   = id & 31;
    const int qi   = ((id >> 5) + bh) & 31;   // balance tile-count across CUs
    const int q0   = qi * 32;
    const int b    = bh >> 4;
    const int h    = bh & 15;
    const int hoff = h * DH;

    const int lane = tid & 63;
    const int wave = tid >> 6;
    const int fr   = lane & 15;
    const int fg   = lane >> 4;
    const int mi   = wave >> 1;
    const int nqk  = wave & 1;
    const int nf0  = (wave & 1) * 2;
    const int tk  = tid >> 3;
    const int ck  = (tid & 7) * 8;
    const int iq  = tid >> 2;
    const int cq4 = (tid & 3) * 16;
    const int sr  = tid >> 3;
    const int sc0 = (tid & 7) * 4;

    {   // stage q once (already bf16)
        const short* qp = q + ((size_t)(b * SS + q0 + tk)) * DD + hoff + ck;
        *(s16x8*)&q_s[tk][ck] = *(const s16x8*)qp;
    }
    if (tid < 32) { row_m[tid] = -INFINITY; row_l[tid] = 0.0f; }

    const int t_end  = q0 + 32 + MEM;
    const int u0base = SS - 1 - (q0 + 31);

    s16x8 kf, vf, rfA, rfB;
    auto loadT = [&](int t0) {
        kf = *(const s16x8*)(k + ((size_t)(b * TT + t0 + tk)) * kstr + hoff + ck);
        vf = *(const s16x8*)(v + ((size_t)(b * TT + t0 + tk)) * kstr + hoff + ck);
        int u = t0 + u0base + iq;
        u = u < 0 ? 0 : (u > TT - 1 ? TT - 1 : u);   // clamped rows are masked-only
        const short* rp = Qr + (size_t)u * DD + hoff + cq4;
        rfA = *(const s16x8*)rp;
        rfB = *(const s16x8*)(rp + 8);
    };
    loadT(0);

    __syncthreads();
    s16x8 aq0 = *(const s16x8*)&q_s[16 * mi + fr][fg * 8];
    s16x8 aq1 = *(const s16x8*)&q_s[16 * mi + fr][32 + fg * 8];

    f32x4 opv0 = {0,0,0,0}, opv1 = {0,0,0,0};

    for (int t0 = 0; t0 < t_end; t0 += 32) {
        __syncthreads();
        {   // staged regs -> LDS
            *(s16x8*)&k_s[tk][ck] = kf;
            const int tsw = tk ^ (((ck >> 3) & 3) << 3);
            vT_s[ck + 0][tsw] = vf[0];
            vT_s[ck + 1][tsw] = vf[1];
            vT_s[ck + 2][tsw] = vf[2];
            vT_s[ck + 3][tsw] = vf[3];
            vT_s[ck + 4][tsw] = vf[4];
            vT_s[ck + 5][tsw] = vf[5];
            vT_s[ck + 6][tsw] = vf[6];
            vT_s[ck + 7][tsw] = vf[7];
            *(s16x8*)&qr_s[iq][cq4]     = rfA;
            *(s16x8*)&qr_s[iq][cq4 + 8] = rfB;
        }
        if (t0 + 32 < t_end) loadT(t0 + 32);   // T14: issue early
        __syncthreads();

        {   // QK + QR MFMAs -> f32 score tiles
            s16x8 b0 = *(const s16x8*)&k_s[16 * nqk + fr][fg * 8];
            s16x8 b1 = *(const s16x8*)&k_s[16 * nqk + fr][32 + fg * 8];
            f32x4 ca = {0,0,0,0};
            ca = __builtin_amdgcn_mfma_f32_16x16x32_bf16(aq0, b0, ca, 0, 0, 0);
            ca = __builtin_amdgcn_mfma_f32_16x16x32_bf16(aq1, b1, ca, 0, 0, 0);
            #pragma unroll
            for (int rg = 0; rg < 4; ++rg)
                a_t[16 * mi + 4 * fg + rg][16 * nqk + fr] = ca[rg];
            #pragma unroll
            for (int i = 0; i < 2; ++i) {
                const int nf = nf0 + i;
                s16x8 c0 = *(const s16x8*)&qr_s[16 * nf + fr][fg * 8];
                s16x8 c1 = *(const s16x8*)&qr_s[16 * nf + fr][32 + fg * 8];
                f32x4 cb = {0,0,0,0};
                cb = __builtin_amdgcn_mfma_f32_16x16x32_bf16(aq0, c0, cb, 0, 0, 0);
                cb = __builtin_amdgcn_mfma_f32_16x16x32_bf16(aq1, c1, cb, 0, 0, 0);
                #pragma unroll
                for (int rg = 0; rg < 4; ++rg)
                    b_t[16 * mi + 4 * fg + rg][16 * nf + fr] = cb[rg];
            }
        }
        __syncthreads();

        {   // online softmax (f32), P -> bf16
            const int s_glob = q0 + sr;
            float sv[4];
            #pragma unroll
            for (int j = 0; j < 4; ++j) {
                const int c = sc0 + j;
                float scv = (a_t[sr][c] + b_t[sr][c + 31 - sr]) * 0.125f;
                sv[j] = (t0 + c > s_glob + MEM) ? -1e30f : scv;
            }
            float mx = fmaxf(fmaxf(sv[0], sv[1]), fmaxf(sv[2], sv[3]));
            mx = fmaxf(mx, __shfl_xor(mx, 1, 64));
            mx = fmaxf(mx, __shfl_xor(mx, 2, 64));
            mx = fmaxf(mx, __shfl_xor(mx, 4, 64));
            const float mo = row_m[sr];
            const float mn = fmaxf(mo, mx);
            const float scl = __expf(mo - mn);
            float sum = 0.0f;
            s16x4 pp;
            #pragma unroll
            for (int j = 0; j < 4; ++j) {
                float e = __expf(sv[j] - mn);
                sum += e;
                pp[j] = f2bf(e);
            }
            sum += __shfl_xor(sum, 1, 64);
            sum += __shfl_xor(sum, 2, 64);
            sum += __shfl_xor(sum, 4, 64);
            if ((tid & 7) == 0) {
                row_m[sr]  = mn;
                row_sc[sr] = scl;
                row_l[sr]  = row_l[sr] * scl + sum;
            }
            *(s16x4*)&p_s[sr][sc0] = pp;
        }
        __syncthreads();

        {   // PV: rescale acc, then acc += P @ V
            f32x4 scv;
            #pragma unroll
            for (int rg = 0; rg < 4; ++rg) scv[rg] = row_sc[16 * mi + 4 * fg + rg];
            #pragma unroll
            for (int rg = 0; rg < 4; ++rg) { opv0[rg] *= scv[rg]; opv1[rg] *= scv[rg]; }
            s16x8 ap = *(const s16x8*)&p_s[16 * mi + fr][fg * 8];
            const int d0 = 16 * nf0 + fr;
            const int d1 = d0 + 16;
            s16x8 bv0 = *(const s16x8*)&vT_s[d0][(fg ^ ((d0 >> 3) & 3)) * 8];
            s16x8 bv1 = *(const s16x8*)&vT_s[d1][(fg ^ ((d1 >> 3) & 3)) * 8];
            opv0 = __builtin_amdgcn_mfma_f32_16x16x32_bf16(ap, bv0, opv0, 0, 0, 0);
            opv1 = __builtin_amdgcn_mfma_f32_16x16x32_bf16(ap, bv1, opv1, 0, 0, 0);
        }
    }

    __syncthreads();
    {   // epilogue: divide by denom, store bf16
        #pragma unroll
        for (int rg = 0; rg < 4; ++rg) {
            const int row = 16 * mi + 4 * fg + rg;
            const float inv = 1.0f / row_l[row];
            short* op = ctx + ((size_t)(b * SS + q0 + row)) * DD + hoff;
            op[16 * nf0 + fr]      = f2bf(opv0[rg] * inv);
            op[16 * nf0 + 16 + fr] = f2bf(opv1[rg] * inv);
        }
    }
}

// ---------------- add + LayerNorm, dual f32 + bf16 output ----------------
__global__ __launch_bounds__(256) void addln_kernel(
    const float* __restrict__ a, const float* __restrict__ b,
    const float* __restrict__ g, const float* __restrict__ be,
    float* __restrict__ out32, short* __restrict__ outbf)
{
    __shared__ float red[8];
    const int row = blockIdx.x;
    const int tid = threadIdx.x;
    const size_t base = (size_t)row * DD;
    const int c = tid * 4;
    float4 xa = *(const float4*)(a + base + c);
    float4 xb = *(const float4*)(b + base + c);
    float x0 = xa.x + xb.x, x1 = xa.y + xb.y, x2 = xa.z + xb.z, x3 = xa.w + xb.w;
    float s  = x0 + x1 + x2 + x3;
    float sq = x0 * x0 + x1 * x1 + x2 * x2 + x3 * x3;
    #pragma unroll
    for (int o = 32; o > 0; o >>= 1) {
        s  += __shfl_down(s, o, 64);
        sq += __shfl_down(sq, o, 64);
    }
    const int wv = tid >> 6;
    if ((tid & 63) == 0) { red[wv * 2] = s; red[wv * 2 + 1] = sq; }
    __syncthreads();
    float ts = red[0] + red[2] + red[4] + red[6];
    float tq = red[1] + red[3] + red[5] + red[7];
    float mu  = ts * (1.0f / DD);
    float var = tq * (1.0f / DD) - mu * mu;
    float rs  = rsqrtf(var + 1e-5f);
    float4 gv = *(const float4*)(g + c);
    float4 bv = *(const float4*)(be + c);
    float4 o4;
    o4.x = (x0 - mu) * rs * gv.x + bv.x;
    o4.y = (x1 - mu) * rs * gv.y + bv.y;
    o4.z = (x2 - mu) * rs * gv.z + bv.z;
    o4.w = (x3 - mu) * rs * gv.w + bv.w;
    *(float4*)(out32 + base + c) = o4;
    short4 ob;
    ob.x = f2bf(o4.x); ob.y = f2bf(o4.y); ob.z = f2bf(o4.z); ob.w = f2bf(o4.w);
    *(short4*)(outbf + base + c) = ob;
}

// ---------------- embedding gather * sqrt(D), dual output ----------------
__global__ __launch_bounds__(256) void embed_kernel(
    const int* __restrict__ inp, const float* __restrict__ emb,
    float* __restrict__ x32, short* __restrict__ xbf)
{
    const int row = blockIdx.x;
    const int c = threadIdx.x * 4;
    const int idx = inp[row];
    float4 vv = *(const float4*)(emb + (size_t)idx * DD + c);
    vv.x *= 32.0f; vv.y *= 32.0f; vv.z *= 32.0f; vv.w *= 32.0f;
    *(float4*)(x32 + (size_t)row * DD + c) = vv;
    short4 ob;
    ob.x = f2bf(vv.x); ob.y = f2bf(vv.y); ob.z = f2bf(vv.z); ob.w = f2bf(vv.w);
    *(short4*)(xbf + (size_t)row * DD + c) = ob;
}

// ---------------- concat mems[l] (f32) and x (bf16) -> xt (bf16) ----------
__global__ __launch_bounds__(256) void concat_kernel(
    const float* __restrict__ mems_l, const short* __restrict__ xbf,
    short* __restrict__ xt)
{
    size_t i = ((size_t)blockIdx.x * 256 + threadIdx.x) * 8;
    size_t bt = i / DD;
    int d = (int)(i - bt * DD);
    int b = (int)(bt / TT);
    int t = (int)(bt - (size_t)b * TT);
    s16x8 o;
    if (t < MEM) {
        const float* mp = mems_l + ((size_t)(b * MEM + t)) * DD + d;
        float4 a0 = *(const float4*)mp;
        float4 a1 = *(const float4*)(mp + 4);
        o[0] = f2bf(a0.x); o[1] = f2bf(a0.y); o[2] = f2bf(a0.z); o[3] = f2bf(a0.w);
        o[4] = f2bf(a1.x); o[5] = f2bf(a1.y); o[6] = f2bf(a1.z); o[7] = f2bf(a1.w);
    } else {
        o = *(const s16x8*)(xbf + ((size_t)(b * SS + (t - MEM))) * DD + d);
    }
    *(s16x8*)(xt + i) = o;
}

// ---------------- reversed sinusoidal position encoding (bf16) ------------
__global__ __launch_bounds__(256) void relenc_kernel(short* __restrict__ re)
{
    const int u = blockIdx.x;
    const int p = TT - 1 - u;
    const int i0 = threadIdx.x * 4;
    short4 o;
    #pragma unroll
    for (int j = 0; j < 4; ++j) {
        int i = i0 + j;
        float ex   = (float)(2 * (i >> 1)) * (1.0f / DD);
        float invf = __expf(-ex * 9.210340371976184f);
        float ang  = (float)p * invf;
        float val  = (i & 1) ? cosf(ang) : sinf(ang);
        ((short*)&o)[j] = f2bf(val);
    }
    *(short4*)&re[(size_t)u * DD + i0] = o;
}

extern "C" void kernel_launch(void* const* d_in, const int* in_sizes, int n_in,
                              void* d_out, int out_size, void* d_ws, size_t ws_size,
                              hipStream_t stream)
{
    const int*   inp  = (const int*)d_in[0];
    const float* mems = (const float*)d_in[1];
    const float* emb  = (const float*)d_in[2];
    const float* Wq   = (const float*)d_in[3];
    const float* bq   = (const float*)d_in[4];
    const float* Wke  = (const float*)d_in[5];
    const float* bke  = (const float*)d_in[6];
    const float* Wkr  = (const float*)d_in[7];
    const float* bkr  = (const float*)d_in[8];
    const float* Wv   = (const float*)d_in[9];
    const float* bv   = (const float*)d_in[10];
    const float* Wo   = (const float*)d_in[11];
    const float* bo   = (const float*)d_in[12];
    const float* ln1g = (const float*)d_in[13];
    const float* ln1b = (const float*)d_in[14];
    const float* W1   = (const float*)d_in[15];
    const float* b1   = (const float*)d_in[16];
    const float* W2   = (const float*)d_in[17];
    const float* b2   = (const float*)d_in[18];
    const float* ln2g = (const float*)d_in[19];
    const float* ln2b = (const float*)d_in[20];
    const float* Wh   = (const float*)d_in[21];
    const float* bh   = (const float*)d_in[22];
    const float* Wf   = (const float*)d_in[23];
    const float* bfb  = (const float*)d_in[24];

    // ---- workspace layout (bytes). First ~64 MiB block is transient and is
    // dead by the time transposeF runs, so wft aliases it.
    char* wsb = (char*)d_ws;
    size_t off = 0;
    auto alloc = [&](size_t bytes) { char* p = wsb + off; off += (bytes + 255) & ~(size_t)255; return p; };
    float* h132  = (float*)alloc((size_t)BB*SS*DD*4);
    float* ao32  = (float*)alloc((size_t)BB*SS*DD*4);
    float* ff232 = (float*)alloc((size_t)BB*SS*DD*4);
    short* xt    = (short*)alloc((size_t)BB*TT*DD*2);
    short* qb    = (short*)alloc((size_t)BB*SS*DD*2);
    short* kvb   = (short*)alloc((size_t)BB*TT*DD*2*2);   // [B*T][2048]: k | v
    short* qr    = (short*)alloc((size_t)TT*DD*2);
    short* ctxb  = (short*)alloc((size_t)BB*SS*DD*2);
    short* ff1   = (short*)alloc((size_t)BB*SS*DD*2);
    // end of transient block
    float* x32   = (float*)alloc((size_t)BB*SS*DD*4);
    short* x_bf  = (short*)alloc((size_t)BB*SS*DD*2);
    short* whout = (short*)alloc((size_t)BB*SS*DD*2);
    short* rel   = (short*)alloc((size_t)TT*DD*2);
    short* wt7   = (short*)alloc((size_t)7*DD*DD*2);
    short* wft   = (short*)h132;   // aliases transient block (needs 62.5 MiB)

    relenc_kernel<<<TT, 256, 0, stream>>>(rel);
    embed_kernel<<<BB * SS, 256, 0, stream>>>(inp, emb, x32, x_bf);

    const size_t WOFF = (size_t)DD * DD;
    // grids (1D, swizzled inside kernel): <4,2> = 128x64 tile, <4,4> = 128x128
    const int gS   = (DD / 64) * ((BB * SS) / 128);       // 16*16  = 256
    const int gKV  = ((2 * DD) / 128) * ((BB * TT) / 128);// 16*32  = 512
    const int nbyS = (BB * SS) / 128;                     // 16
    const int nbyKV= (BB * TT) / 128;                     // 32

    for (int l = 0; l < LL; ++l) {
        const size_t wo  = (size_t)l * DD * DD;
        const size_t bo_ = (size_t)l * DD;
        // z-order: 0=Wq 1=Wke 2=Wv (adjacent -> fused kv weight) 3=Wkr 4=Wo 5=W1 6=W2
        transpose7_kernel<<<dim3(32, 32, 7), 256, 0, stream>>>(
            Wq + wo, Wke + wo, Wv + wo, Wkr + wo, Wo + wo, W1 + wo, W2 + wo, wt7);
        concat_kernel<<<(BB * TT * DD / 8) / 256, 256, 0, stream>>>(
            mems + (size_t)l * BB * MEM * DD, x_bf, xt);
        gemm_bf16<4,2><<<gS,  256, 0, stream>>>(x_bf, wt7 + 0*WOFF, bq + bo_, bq + bo_, DD, qb, DD, DD, nbyS, 0, 1);
        gemm_bf16<4,4><<<gKV, 256, 0, stream>>>(xt,   wt7 + 1*WOFF, bke + bo_, bv + bo_, DD, kvb, 2*DD, DD, nbyKV, 0, 1);
        gemm_bf16<4,2><<<gS,  256, 0, stream>>>(rel,  wt7 + 3*WOFF, bkr + bo_, bkr + bo_, DD, qr, DD, DD, nbyS, 0, 1);
        attn_kernel<<<dim3((SS / 32) * BB * NH), 256, 0, stream>>>(
            qb, kvb, kvb + DD, qr, ctxb, 2 * DD);
        gemm_bf16<4,2><<<gS, 256, 0, stream>>>(ctxb, wt7 + 4*WOFF, bo + bo_, bo + bo_, DD, ao32, DD, DD, nbyS, 0, 0);
        addln_kernel<<<BB * SS, 256, 0, stream>>>(x32, ao32, ln1g + bo_, ln1b + bo_, h132, (short*)x_bf);
        gemm_bf16<4,2><<<gS, 256, 0, stream>>>(x_bf, wt7 + 5*WOFF, b1 + bo_, b1 + bo_, DD, ff1,   DD, DD, nbyS, 1, 1);
        gemm_bf16<4,2><<<gS, 256, 0, stream>>>(ff1,  wt7 + 6*WOFF, b2 + bo_, b2 + bo_, DD, ff232, DD, DD, nbyS, 0, 0);
        addln_kernel<<<BB * SS, 256, 0, stream>>>(h132, ff232, ln2g + bo_, ln2b + bo_, x32, x_bf);
    }

    transpose7_kernel<<<dim3(32, 32, 1), 256, 0, stream>>>(
        Wh, Wh, Wh, Wh, Wh, Wh, Wh, wt7);
    transposeF_kernel<<<dim3(VV / 32, DD / 32), 256, 0, stream>>>(Wf, wft);
    gemm_bf16<4,2><<<gS, 256, 0, stream>>>(x_bf, wt7, bh, bh, DD, whout, DD, DD, nbyS, 1, 1);
    gemm_bf16<4,4><<<dim3((VV / 128) * ((BB * SS) / 128)), 256, 0, stream>>>(
        whout, wft, bfb, bfb, VV, (float*)d_out, VV, DD, (BB * SS) / 128, 0, 0);
}

// Round 6
// 1415.064 us; speedup vs baseline: 1.1279x; 1.1279x over previous
//
#include <hip/hip_runtime.h>
#include <hip/hip_bf16.h>
#include <math.h>

typedef __attribute__((ext_vector_type(4))) float f32x4;
typedef __attribute__((ext_vector_type(8))) short s16x8;

#define BB 2
#define SS 1024
#define MEM 1024
#define DD 1024
#define LL 4
#define VV 32000
#define TT 2048
#define NH 16
#define DH 64

__device__ __forceinline__ short f2bf(float f) {
    unsigned u = __float_as_uint(f);
    u += 0x7fffu + ((u >> 16) & 1u);   // round-to-nearest-even
    return (short)(u >> 16);
}

__device__ __forceinline__ float gelu_f(float x) {
    return 0.5f * x * (1.0f + erff(x * 0.70710678118654752f));
}

__device__ __forceinline__ void gll16(const short* g, short* l) {
    __builtin_amdgcn_global_load_lds(
        (__attribute__((address_space(1))) void*)(short*)g,
        (__attribute__((address_space(3))) void*)l, 16, 0, 0);
}

// ---------------- GEMM: C(M,N) = act(A @ Bt^T + bias), bf16 inputs --------
// Single-buffered LDS, 2 barriers per K-step (R3-proven structure) + XCD
// swizzle (R4-proven FETCH fix). LDS slot layout (conflict-free b128 reads):
// slot s (16B) = [block16 = s>>7][kslice = (s>>4)&7][fr = s&15].
template<int WM, int WN>
__global__ __launch_bounds__(256) void gemm_bf16(
    const short* __restrict__ A, const short* __restrict__ Bt,
    const float* __restrict__ bias, const float* __restrict__ bias2,
    int nsplit, void* __restrict__ Cv, int N, int K, int nby, int act, int obf)
{
    constexpr int BM = WM * 32, BN = WN * 32;
    constexpr int NA = BM / 32, NB = BN / 32;
    __shared__ short a_s[BM * 64];
    __shared__ short b_s[BN * 64];
    const int tid  = threadIdx.x;
    const int lane = tid & 63;
    const int wave = tid >> 6;
    const int wr = wave >> 1, wc = wave & 1;
    const int fr = lane & 15, fg = lane >> 4;

    const int nwg = gridDim.x;
    const int bid = blockIdx.x;
    const int swz = ((nwg & 7) == 0) ? ((bid & 7) * (nwg >> 3) + (bid >> 3)) : bid;
    const size_t m0 = (size_t)(swz % nby) * BM;   // M fastest -> B-panel reuse
    const size_t n0 = (size_t)(swz / nby) * BN;

    const short* gA[NA]; short* lA[NA];
    const short* gB[NB]; short* lB[NB];
    #pragma unroll
    for (int i = 0; i < NA; ++i) {
        const int s   = i * 256 + tid;
        const int row = (s >> 7) * 16 + (s & 15);
        const int kof = ((s >> 4) & 7) * 8;
        gA[i] = A + (m0 + row) * (size_t)K + kof;
        lA[i] = &a_s[s * 8];
    }
    #pragma unroll
    for (int i = 0; i < NB; ++i) {
        const int s   = i * 256 + tid;
        const int nn  = (s >> 7) * 16 + (s & 15);
        const int kof = ((s >> 4) & 7) * 8;
        gB[i] = Bt + (n0 + nn) * (size_t)K + kof;
        lB[i] = &b_s[s * 8];
    }

    f32x4 acc[WM][WN] = {};

    #pragma unroll
    for (int i = 0; i < NA; ++i) gll16(gA[i], lA[i]);
    #pragma unroll
    for (int i = 0; i < NB; ++i) gll16(gB[i], lB[i]);

    const int nt = K >> 6;
    for (int t = 0; t < nt; ++t) {
        __syncthreads();   // staged tile visible (vmcnt(0) drained here)
        s16x8 af[WM][2], bf[WN][2];
        #pragma unroll
        for (int mi = 0; mi < WM; ++mi)
            #pragma unroll
            for (int h = 0; h < 2; ++h)
                af[mi][h] = *(const s16x8*)&a_s[((wr*WM + mi)*128 + (h*4 + fg)*16 + fr) * 8];
        #pragma unroll
        for (int ni = 0; ni < WN; ++ni)
            #pragma unroll
            for (int h = 0; h < 2; ++h)
                bf[ni][h] = *(const s16x8*)&b_s[((wc*WN + ni)*128 + (h*4 + fg)*16 + fr) * 8];
        if (t + 1 < nt) {
            __syncthreads();   // frag reads retired -> safe to restage
            const int koff = (t + 1) << 6;
            #pragma unroll
            for (int i = 0; i < NA; ++i) gll16(gA[i] + koff, lA[i]);
            #pragma unroll
            for (int i = 0; i < NB; ++i) gll16(gB[i] + koff, lB[i]);
        }
        #pragma unroll
        for (int mi = 0; mi < WM; ++mi)
            #pragma unroll
            for (int ni = 0; ni < WN; ++ni) {
                acc[mi][ni] = __builtin_amdgcn_mfma_f32_16x16x32_bf16(
                    af[mi][0], bf[ni][0], acc[mi][ni], 0, 0, 0);
                acc[mi][ni] = __builtin_amdgcn_mfma_f32_16x16x32_bf16(
                    af[mi][1], bf[ni][1], acc[mi][ni], 0, 0, 0);
            }
    }

    float* Cf = (float*)Cv;
    short* Cb = (short*)Cv;
    #pragma unroll
    for (int mi = 0; mi < WM; ++mi) {
        #pragma unroll
        for (int ni = 0; ni < WN; ++ni) {
            const size_t r0 = m0 + wr*WM*16 + mi*16 + fg*4;
            const size_t c  = n0 + wc*WN*16 + ni*16 + fr;
            const float bb = (c < (size_t)nsplit) ? bias[c] : bias2[c - nsplit];
            #pragma unroll
            for (int rg = 0; rg < 4; ++rg) {
                float vv = acc[mi][ni][rg] + bb;
                if (act) vv = gelu_f(vv);
                if (obf) Cb[(r0 + rg)*(size_t)N + c] = f2bf(vv);
                else     Cf[(r0 + rg)*(size_t)N + c] = vv;
            }
        }
    }
}

// ---------------- weight transpose+convert: W[k][n] f32 -> Wt[n][k] bf16 ----
__global__ __launch_bounds__(256) void transpose7_kernel(
    const float* w0, const float* w1, const float* w2, const float* w3,
    const float* w4, const float* w5, const float* w6, short* out)
{
    __shared__ float t[32][33];
    const int z = blockIdx.z;
    const float* W;
    switch (z) {
        case 0: W = w0; break; case 1: W = w1; break; case 2: W = w2; break;
        case 3: W = w3; break; case 4: W = w4; break; case 5: W = w5; break;
        default: W = w6; break;
    }
    short* O = out + (size_t)z * DD * DD;
    const int tid = threadIdx.x;
    const int k0 = blockIdx.y * 32, n0 = blockIdx.x * 32;
    const int r = tid >> 3, c4 = (tid & 7) * 4;
    float4 v = *(const float4*)&W[(size_t)(k0 + r) * DD + n0 + c4];
    t[r][c4+0] = v.x; t[r][c4+1] = v.y; t[r][c4+2] = v.z; t[r][c4+3] = v.w;
    __syncthreads();
    short4 o;
    o.x = f2bf(t[c4+0][r]); o.y = f2bf(t[c4+1][r]);
    o.z = f2bf(t[c4+2][r]); o.w = f2bf(t[c4+3][r]);
    *(short4*)&O[(size_t)(n0 + r) * DD + k0 + c4] = o;
}

__global__ __launch_bounds__(256) void transposeF_kernel(
    const float* __restrict__ W, short* __restrict__ O)
{
    __shared__ float t[32][33];
    const int tid = threadIdx.x;
    const int k0 = blockIdx.y * 32, n0 = blockIdx.x * 32;
    const int r = tid >> 3, c4 = (tid & 7) * 4;
    float4 v = *(const float4*)&W[(size_t)(k0 + r) * VV + n0 + c4];
    t[r][c4+0] = v.x; t[r][c4+1] = v.y; t[r][c4+2] = v.z; t[r][c4+3] = v.w;
    __syncthreads();
    short4 o;
    o.x = f2bf(t[c4+0][r]); o.y = f2bf(t[c4+1][r]);
    o.z = f2bf(t[c4+2][r]); o.w = f2bf(t[c4+3][r]);
    *(short4*)&O[(size_t)(n0 + r) * DD + k0 + c4] = o;
}

// ---------------- MFMA flash attention, QB=64, shift-scatter --------------
// Per block: 64 q rows of one (b,h); wave w owns rows [16w,16w+16).
// Per 32-key tile: QK (4 MFMA/wave) -> a_t; QR over the 95-wide Qr window
// using only the 3 contributing n-frags (6 MFMA/wave), output SCATTERED
// directly into shifted position b_ts[r][wi-63+r]; softmax f32; PV (4 MFMA).
__global__ __launch_bounds__(256) void attn_kernel(
    const short* __restrict__ q, const short* __restrict__ k,
    const short* __restrict__ v, const short* __restrict__ Qr,
    short* __restrict__ ctx, int kstr, int qstr)
{
    __shared__ short k_s[32][72];
    __shared__ short qr_s[96][72];
    __shared__ short vT_s[64][40];   // [d][t^X], X = ((d>>3)&3)<<3
    __shared__ float a_t[64][33];
    __shared__ float b_ts[64][33];
    __shared__ short p_s[64][40];
    __shared__ float row_m[64], row_l[64], row_sc[64];

    const int tid  = threadIdx.x;
    const int id   = blockIdx.x;
    const int bh   = id & 31;
    const int qi   = ((id >> 5) + bh) & 15;   // balance tile-count across CUs
    const int q0   = qi * 64;
    const int b    = bh >> 4;
    const int h    = bh & 15;
    const int hoff = h * DH;

    const int lane = tid & 63;
    const int wave = tid >> 6;
    const int fr   = lane & 15;
    const int fg   = lane >> 4;
    // staging maps
    const int tk  = tid >> 3, ck = (tid & 7) * 8;          // k/v rows 0..31
    const int iq  = tid >> 2, cq = (tid & 3) * 16;         // qr rows 0..63
    const int iq2 = 64 + (tid >> 3), cq2 = (tid & 7) * 8;  // qr rows 64..95
    const int sr  = tid >> 2, sc0 = (tid & 3) * 8;         // softmax

    // persistent q frags straight from global (no LDS roundtrip)
    const short* qrow = q + ((size_t)(b * SS + q0 + 16 * wave + fr)) * DD + hoff;
    s16x8 aq0 = *(const s16x8*)(qrow + fg * 8);
    s16x8 aq1 = *(const s16x8*)(qrow + 32 + fg * 8);

    if (tid < 64) { row_m[tid] = -INFINITY; row_l[tid] = 0.0f; }

    const int t_end = q0 + 64 + MEM;          // == 2048 at q0=960 (never past TT)
    const int u0b   = SS - 1 - (q0 + 63);     // u = t0 + u0b + wi

    s16x8 kf, vf, rA, rB, rC;
    auto loadT = [&](int t0) {
        kf = *(const s16x8*)(k + ((size_t)(b * TT + t0 + tk)) * kstr + hoff + ck);
        vf = *(const s16x8*)(v + ((size_t)(b * TT + t0 + tk)) * kstr + hoff + ck);
        int u1 = t0 + u0b + iq;
        u1 = u1 < 0 ? 0 : (u1 > TT - 1 ? TT - 1 : u1);   // clamped -> masked-only
        const short* rp = Qr + (size_t)u1 * qstr + hoff + cq;
        rA = *(const s16x8*)rp;
        rB = *(const s16x8*)(rp + 8);
        int u2 = t0 + u0b + iq2;
        u2 = u2 < 0 ? 0 : (u2 > TT - 1 ? TT - 1 : u2);
        rC = *(const s16x8*)(Qr + (size_t)u2 * qstr + hoff + cq2);
    };
    loadT(0);

    f32x4 opv[4] = {};
    const int nlo = 3 - wave, nhi = 5 - wave;   // contributing QR frags

    for (int t0 = 0; t0 < t_end; t0 += 32) {
        __syncthreads();   // prev tile's LDS reads retired
        {   // staged regs -> LDS
            *(s16x8*)&k_s[tk][ck] = kf;
            const int tsw = tk ^ (((ck >> 3) & 3) << 3);
            vT_s[ck + 0][tsw] = vf[0];
            vT_s[ck + 1][tsw] = vf[1];
            vT_s[ck + 2][tsw] = vf[2];
            vT_s[ck + 3][tsw] = vf[3];
            vT_s[ck + 4][tsw] = vf[4];
            vT_s[ck + 5][tsw] = vf[5];
            vT_s[ck + 6][tsw] = vf[6];
            vT_s[ck + 7][tsw] = vf[7];
            *(s16x8*)&qr_s[iq][cq]      = rA;
            *(s16x8*)&qr_s[iq][cq + 8]  = rB;
            *(s16x8*)&qr_s[iq2][cq2]    = rC;
        }
        if (t0 + 32 < t_end) loadT(t0 + 32);   // T14: issue early
        __syncthreads();

        {   // QK -> a_t
            #pragma unroll
            for (int n = 0; n < 2; ++n) {
                s16x8 b0 = *(const s16x8*)&k_s[16*n + fr][fg * 8];
                s16x8 b1 = *(const s16x8*)&k_s[16*n + fr][32 + fg * 8];
                f32x4 ca = {0, 0, 0, 0};
                ca = __builtin_amdgcn_mfma_f32_16x16x32_bf16(aq0, b0, ca, 0, 0, 0);
                ca = __builtin_amdgcn_mfma_f32_16x16x32_bf16(aq1, b1, ca, 0, 0, 0);
                #pragma unroll
                for (int rg = 0; rg < 4; ++rg)
                    a_t[16*wave + 4*fg + rg][16*n + fr] = ca[rg];
            }
        }
        {   // QR band -> scatter into shifted position
            #pragma unroll
            for (int n = 0; n < 6; ++n) {
                if (n < nlo || n > nhi) continue;   // wave-uniform
                s16x8 c0 = *(const s16x8*)&qr_s[16*n + fr][fg * 8];
                s16x8 c1 = *(const s16x8*)&qr_s[16*n + fr][32 + fg * 8];
                f32x4 cb = {0, 0, 0, 0};
                cb = __builtin_amdgcn_mfma_f32_16x16x32_bf16(aq0, c0, cb, 0, 0, 0);
                cb = __builtin_amdgcn_mfma_f32_16x16x32_bf16(aq1, c1, cb, 0, 0, 0);
                #pragma unroll
                for (int rg = 0; rg < 4; ++rg) {
                    const int r  = 16*wave + 4*fg + rg;
                    const int tl = 16*n + fr - 63 + r;
                    if ((unsigned)tl < 32u) b_ts[r][tl] = cb[rg];
                }
            }
        }
        __syncthreads();

        {   // online softmax (f32), P -> bf16
            const int sg = q0 + sr;
            float sv[8];
            #pragma unroll
            for (int j = 0; j < 8; ++j) {
                const int c = sc0 + j;
                float x = (a_t[sr][c] + b_ts[sr][c]) * 0.125f;
                sv[j] = (t0 + c > sg + MEM) ? -1e30f : x;
            }
            float mx = sv[0];
            #pragma unroll
            for (int j = 1; j < 8; ++j) mx = fmaxf(mx, sv[j]);
            mx = fmaxf(mx, __shfl_xor(mx, 1, 64));
            mx = fmaxf(mx, __shfl_xor(mx, 2, 64));
            const float mo = row_m[sr];
            const float mn = fmaxf(mo, mx);
            const float scl = __expf(mo - mn);
            float sum = 0.0f;
            s16x8 pp;
            #pragma unroll
            for (int j = 0; j < 8; ++j) {
                float e = __expf(sv[j] - mn);
                sum += e;
                pp[j] = f2bf(e);
            }
            sum += __shfl_xor(sum, 1, 64);
            sum += __shfl_xor(sum, 2, 64);
            if ((tid & 3) == 0) {
                row_m[sr]  = mn;
                row_sc[sr] = scl;
                row_l[sr]  = row_l[sr] * scl + sum;
            }
            *(s16x8*)&p_s[sr][sc0] = pp;
        }
        __syncthreads();

        {   // PV: rescale acc, then acc += P @ V
            f32x4 scv;
            #pragma unroll
            for (int rg = 0; rg < 4; ++rg) scv[rg] = row_sc[16*wave + 4*fg + rg];
            #pragma unroll
            for (int n = 0; n < 4; ++n)
                #pragma unroll
                for (int rg = 0; rg < 4; ++rg) opv[n][rg] *= scv[rg];
            s16x8 ap = *(const s16x8*)&p_s[16*wave + fr][fg * 8];
            #pragma unroll
            for (int n = 0; n < 4; ++n) {
                const int d = 16*n + fr;
                s16x8 bv = *(const s16x8*)&vT_s[d][(fg ^ ((d >> 3) & 3)) * 8];
                opv[n] = __builtin_amdgcn_mfma_f32_16x16x32_bf16(ap, bv, opv[n], 0, 0, 0);
            }
        }
    }

    {   // epilogue: divide by denom, store bf16
        #pragma unroll
        for (int rg = 0; rg < 4; ++rg) {
            const int r = 16*wave + 4*fg + rg;
            const float inv = 1.0f / row_l[r];
            short* op = ctx + ((size_t)(b * SS + q0 + r)) * DD + hoff;
            #pragma unroll
            for (int n = 0; n < 4; ++n)
                op[16*n + fr] = f2bf(opv[n][rg] * inv);
        }
    }
}

// ---------------- add + LayerNorm, dual f32 + bf16 output ----------------
__global__ __launch_bounds__(256) void addln_kernel(
    const float* __restrict__ a, const float* __restrict__ b,
    const float* __restrict__ g, const float* __restrict__ be,
    float* __restrict__ out32, short* __restrict__ outbf)
{
    __shared__ float red[8];
    const int row = blockIdx.x;
    const int tid = threadIdx.x;
    const size_t base = (size_t)row * DD;
    const int c = tid * 4;
    float4 xa = *(const float4*)(a + base + c);
    float4 xb = *(const float4*)(b + base + c);
    float x0 = xa.x + xb.x, x1 = xa.y + xb.y, x2 = xa.z + xb.z, x3 = xa.w + xb.w;
    float s  = x0 + x1 + x2 + x3;
    float sq = x0 * x0 + x1 * x1 + x2 * x2 + x3 * x3;
    #pragma unroll
    for (int o = 32; o > 0; o >>= 1) {
        s  += __shfl_down(s, o, 64);
        sq += __shfl_down(sq, o, 64);
    }
    const int wv = tid >> 6;
    if ((tid & 63) == 0) { red[wv * 2] = s; red[wv * 2 + 1] = sq; }
    __syncthreads();
    float ts = red[0] + red[2] + red[4] + red[6];
    float tq = red[1] + red[3] + red[5] + red[7];
    float mu  = ts * (1.0f / DD);
    float var = tq * (1.0f / DD) - mu * mu;
    float rs  = rsqrtf(var + 1e-5f);
    float4 gv = *(const float4*)(g + c);
    float4 bv = *(const float4*)(be + c);
    float4 o4;
    o4.x = (x0 - mu) * rs * gv.x + bv.x;
    o4.y = (x1 - mu) * rs * gv.y + bv.y;
    o4.z = (x2 - mu) * rs * gv.z + bv.z;
    o4.w = (x3 - mu) * rs * gv.w + bv.w;
    *(float4*)(out32 + base + c) = o4;
    short4 ob;
    ob.x = f2bf(o4.x); ob.y = f2bf(o4.y); ob.z = f2bf(o4.z); ob.w = f2bf(o4.w);
    *(short4*)(outbf + base + c) = ob;
}

// ---------------- embedding gather * sqrt(D), dual output ----------------
__global__ __launch_bounds__(256) void embed_kernel(
    const int* __restrict__ inp, const float* __restrict__ emb,
    float* __restrict__ x32, short* __restrict__ xbf)
{
    const int row = blockIdx.x;
    const int c = threadIdx.x * 4;
    const int idx = inp[row];
    float4 vv = *(const float4*)(emb + (size_t)idx * DD + c);
    vv.x *= 32.0f; vv.y *= 32.0f; vv.z *= 32.0f; vv.w *= 32.0f;
    *(float4*)(x32 + (size_t)row * DD + c) = vv;
    short4 ob;
    ob.x = f2bf(vv.x); ob.y = f2bf(vv.y); ob.z = f2bf(vv.z); ob.w = f2bf(vv.w);
    *(short4*)(xbf + (size_t)row * DD + c) = ob;
}

// ---------------- concat mems[l] (f32) and x (bf16) -> xt (bf16) ----------
__global__ __launch_bounds__(256) void concat_kernel(
    const float* __restrict__ mems_l, const short* __restrict__ xbf,
    short* __restrict__ xt)
{
    size_t i = ((size_t)blockIdx.x * 256 + threadIdx.x) * 8;
    size_t bt = i / DD;
    int d = (int)(i - bt * DD);
    int b = (int)(bt / TT);
    int t = (int)(bt - (size_t)b * TT);
    s16x8 o;
    if (t < MEM) {
        const float* mp = mems_l + ((size_t)(b * MEM + t)) * DD + d;
        float4 a0 = *(const float4*)mp;
        float4 a1 = *(const float4*)(mp + 4);
        o[0] = f2bf(a0.x); o[1] = f2bf(a0.y); o[2] = f2bf(a0.z); o[3] = f2bf(a0.w);
        o[4] = f2bf(a1.x); o[5] = f2bf(a1.y); o[6] = f2bf(a1.z); o[7] = f2bf(a1.w);
    } else {
        o = *(const s16x8*)(xbf + ((size_t)(b * SS + (t - MEM))) * DD + d);
    }
    *(s16x8*)(xt + i) = o;
}

// ---------------- reversed sinusoidal position encoding (bf16) ------------
__global__ __launch_bounds__(256) void relenc_kernel(short* __restrict__ re)
{
    const int u = blockIdx.x;
    const int p = TT - 1 - u;
    const int i0 = threadIdx.x * 4;
    short4 o;
    #pragma unroll
    for (int j = 0; j < 4; ++j) {
        int i = i0 + j;
        float ex   = (float)(2 * (i >> 1)) * (1.0f / DD);
        float invf = __expf(-ex * 9.210340371976184f);
        float ang  = (float)p * invf;
        float val  = (i & 1) ? cosf(ang) : sinf(ang);
        ((short*)&o)[j] = f2bf(val);
    }
    *(short4*)&re[(size_t)u * DD + i0] = o;
}

extern "C" void kernel_launch(void* const* d_in, const int* in_sizes, int n_in,
                              void* d_out, int out_size, void* d_ws, size_t ws_size,
                              hipStream_t stream)
{
    const int*   inp  = (const int*)d_in[0];
    const float* mems = (const float*)d_in[1];
    const float* emb  = (const float*)d_in[2];
    const float* Wq   = (const float*)d_in[3];
    const float* bq   = (const float*)d_in[4];
    const float* Wke  = (const float*)d_in[5];
    const float* bke  = (const float*)d_in[6];
    const float* Wkr  = (const float*)d_in[7];
    const float* bkr  = (const float*)d_in[8];
    const float* Wv   = (const float*)d_in[9];
    const float* bv   = (const float*)d_in[10];
    const float* Wo   = (const float*)d_in[11];
    const float* bo   = (const float*)d_in[12];
    const float* ln1g = (const float*)d_in[13];
    const float* ln1b = (const float*)d_in[14];
    const float* W1   = (const float*)d_in[15];
    const float* b1   = (const float*)d_in[16];
    const float* W2   = (const float*)d_in[17];
    const float* b2   = (const float*)d_in[18];
    const float* ln2g = (const float*)d_in[19];
    const float* ln2b = (const float*)d_in[20];
    const float* Wh   = (const float*)d_in[21];
    const float* bh   = (const float*)d_in[22];
    const float* Wf   = (const float*)d_in[23];
    const float* bfb  = (const float*)d_in[24];

    // ---- workspace. Transient block (first 68 MB) is dead outside the layer
    // loop: wkr4 (pre-loop) and wft (post-loop) alias its start.
    char* wsb = (char*)d_ws;
    size_t off = 0;
    auto alloc = [&](size_t bytes) { char* p = wsb + off; off += (bytes + 255) & ~(size_t)255; return p; };
    float* h132  = (float*)alloc((size_t)BB*SS*DD*4);
    float* ao32  = (float*)alloc((size_t)BB*SS*DD*4);
    float* ff232 = (float*)alloc((size_t)BB*SS*DD*4);
    short* xt    = (short*)alloc((size_t)BB*TT*DD*2);
    short* qb    = (short*)alloc((size_t)BB*SS*DD*2);
    short* kvb   = (short*)alloc((size_t)BB*TT*DD*2*2);   // [B*T][2048]: k | v
    short* ctxb  = (short*)alloc((size_t)BB*SS*DD*2);
    short* ff1   = (short*)alloc((size_t)BB*SS*DD*2);
    // end transient (68 MB)
    float* x32   = (float*)alloc((size_t)BB*SS*DD*4);
    short* x_bf  = (short*)alloc((size_t)BB*SS*DD*2);
    short* whout = (short*)alloc((size_t)BB*SS*DD*2);
    short* rel   = (short*)alloc((size_t)TT*DD*2);
    short* qr4   = (short*)alloc((size_t)SS*2*4*DD*2);    // [2048][4096] bf16
    short* wt6   = (short*)alloc((size_t)6*DD*DD*2);
    short* wkr4  = (short*)h132;   // 8 MB, pre-loop only
    short* wft   = (short*)h132;   // 62.5 MB, post-loop only

    relenc_kernel<<<TT, 256, 0, stream>>>(rel);
    embed_kernel<<<BB * SS, 256, 0, stream>>>(inp, emb, x32, x_bf);

    const size_t WOFF = (size_t)DD * DD;

    // hoisted: Qr for ALL layers = rel @ [Wkr0^T|..|Wkr3^T], bias = bkr flat
    transpose7_kernel<<<dim3(32, 32, 4), 256, 0, stream>>>(
        Wkr + 0*WOFF, Wkr + 1*WOFF, Wkr + 2*WOFF, Wkr + 3*WOFF, Wq, Wq, Wq, wkr4);
    gemm_bf16<4,4><<<dim3(512), 256, 0, stream>>>(
        rel, wkr4, bkr, bkr, 4*DD, qr4, 4*DD, DD, TT/128, 0, 1);

    // grids: <2,2> 64x64 tile; <4,4> 128x128 tile
    const int gSm = (DD / 64) * ((BB * SS) / 64);          // 512
    const int gKV = ((2 * DD) / 128) * ((BB * TT) / 128);  // 512

    for (int l = 0; l < LL; ++l) {
        const size_t wo  = (size_t)l * DD * DD;
        const size_t bo_ = (size_t)l * DD;
        // wt6 slots: 0=Wq 1=Wke 2=Wv 3=Wo 4=W1 5=W2 (1,2 adjacent -> fused kv)
        transpose7_kernel<<<dim3(32, 32, 6), 256, 0, stream>>>(
            Wq + wo, Wke + wo, Wv + wo, Wo + wo, W1 + wo, W2 + wo, Wq, wt6);
        concat_kernel<<<(BB * TT * DD / 8) / 256, 256, 0, stream>>>(
            mems + (size_t)l * BB * MEM * DD, x_bf, xt);
        gemm_bf16<2,2><<<dim3(gSm), 256, 0, stream>>>(
            x_bf, wt6 + 0*WOFF, bq + bo_, bq + bo_, DD, qb, DD, DD, (BB*SS)/64, 0, 1);
        gemm_bf16<4,4><<<dim3(gKV), 256, 0, stream>>>(
            xt, wt6 + 1*WOFF, bke + bo_, bv + bo_, DD, kvb, 2*DD, DD, (BB*TT)/128, 0, 1);
        attn_kernel<<<dim3((SS / 64) * BB * NH), 256, 0, stream>>>(
            qb, kvb, kvb + DD, qr4 + (size_t)l * DD, ctxb, 2 * DD, 4 * DD);
        gemm_bf16<2,2><<<dim3(gSm), 256, 0, stream>>>(
            ctxb, wt6 + 3*WOFF, bo + bo_, bo + bo_, DD, ao32, DD, DD, (BB*SS)/64, 0, 0);
        addln_kernel<<<BB * SS, 256, 0, stream>>>(x32, ao32, ln1g + bo_, ln1b + bo_, h132, x_bf);
        gemm_bf16<2,2><<<dim3(gSm), 256, 0, stream>>>(
            x_bf, wt6 + 4*WOFF, b1 + bo_, b1 + bo_, DD, ff1, DD, DD, (BB*SS)/64, 1, 1);
        gemm_bf16<2,2><<<dim3(gSm), 256, 0, stream>>>(
            ff1, wt6 + 5*WOFF, b2 + bo_, b2 + bo_, DD, ff232, DD, DD, (BB*SS)/64, 0, 0);
        addln_kernel<<<BB * SS, 256, 0, stream>>>(h132, ff232, ln2g + bo_, ln2b + bo_, x32, x_bf);
    }

    transpose7_kernel<<<dim3(32, 32, 1), 256, 0, stream>>>(
        Wh, Wh, Wh, Wh, Wh, Wh, Wh, wt6);
    transposeF_kernel<<<dim3(VV / 32, DD / 32), 256, 0, stream>>>(Wf, wft);
    gemm_bf16<2,2><<<dim3(gSm), 256, 0, stream>>>(
        x_bf, wt6, bh, bh, DD, whout, DD, DD, (BB*SS)/64, 1, 1);
    gemm_bf16<4,4><<<dim3((VV / 128) * ((BB * SS) / 128)), 256, 0, stream>>>(
        whout, wft, bfb, bfb, VV, (float*)d_out, VV, DD, (BB*SS)/128, 0, 0);
}